// Round 8
// baseline (263.367 us; speedup 1.0000x reference)
//
#include <hip/hip_runtime.h>
#include <stdint.h>

// B=8, C=64, N=4096. Flash attention with Q=K=x^T [N,64], V=x^T W [N,64].
// Round 8: barrier-free flash. xT/sT are 8 MB (L2/L3-hot; FETCH=33MB says HBM
// irrelevant) -> read K/V fragments directly from global (L1/L2), deleting
// Kt/Vt staging, the LDS-DMA, and BOTH __syncthreads. LDS keeps only the
// wave-private P^T round-trip (16 KB/block) -> 6 blocks/CU, launch_bounds
// (256,6) -> ~24 waves/CU vs R5's ~10. KS=8 to fill the capacity.

#define NTOK 4096
#define CCH  64
#define LOG2E 1.44269504088896340736f

typedef float v4f __attribute__((ext_vector_type(4)));
typedef __bf16 v8bf __attribute__((ext_vector_type(8)));
typedef unsigned short v8us __attribute__((ext_vector_type(8)));

__device__ __forceinline__ unsigned short f2bf(float f) {
    union { float f; unsigned int u; } c; c.f = f;
    unsigned int r = c.u + 0x7fffu + ((c.u >> 16) & 1u);   // RNE
    return (unsigned short)(r >> 16);
}

__device__ __forceinline__ v8bf ld8(const unsigned short* p) {
    union { v8us s; v8bf b; } u;
    u.s = *(const v8us*)p;
    return u.b;
}

// pack two f32 -> u32 of (bf16_trunc(a) | bf16_trunc(b)<<16), one v_perm
__device__ __forceinline__ unsigned int pkbf(float a, float b) {
    union { float f; unsigned int u; } ua, ub; ua.f = a; ub.f = b;
    return __builtin_amdgcn_perm(ub.u, ua.u, 0x07060302u);
}

// ---------------------------------------------------------------------------
// Prep: xT[b][n][c] = bf16(x[b][c][n]);  sT[b][d][n] = bf16(sum_c x[b][c][n] W[c][d])
// Grid (64, 8) x 256. Support via MFMA (A=W^T frags, B=x bf16 tile from LDS).
// ---------------------------------------------------------------------------
__global__ __launch_bounds__(256) void prep_kernel(
    const float* __restrict__ x,        // [8][64][4096]
    const float* __restrict__ w,        // [64][64]
    unsigned short* __restrict__ xT,    // [8][4096][64] bf16
    unsigned short* __restrict__ sT)    // [8][64][4096] bf16
{
    __shared__ float Xf[64 * 65];                        // [c][n] f32, stride 65
    __shared__ __align__(16) unsigned short Xb[64 * 64]; // [n][c] bf16, swizzled

    const int tid  = threadIdx.x;
    const int lane = tid & 63;
    const int wv   = __builtin_amdgcn_readfirstlane(tid >> 6);
    const int quad = lane >> 4;
    const int l16  = lane & 15;
    const int b    = blockIdx.y;
    const int n0   = blockIdx.x * 64;

    // ---- phase A: stage x tile [64 c][64 n] f32 into LDS (coalesced) ----
    const float* xb = x + (size_t)b * CCH * NTOK + n0 + lane;
    #pragma unroll
    for (int k = 0; k < 16; ++k) {
        const int c = wv * 16 + k;
        Xf[c * 65 + lane] = xb[(size_t)c * NTOK];
    }
    __syncthreads();

    // ---- phase B: pack bf16 row fragments; write xT (global) + Xb (LDS) ----
    {
        const int n  = tid >> 2;
        const int c0 = (tid & 3) * 16;
        unsigned int pk[8];
        #pragma unroll
        for (int k = 0; k < 8; ++k) {
            const float a  = Xf[(c0 + 2 * k) * 65 + n];
            const float c2 = Xf[(c0 + 2 * k + 1) * 65 + n];
            pk[k] = (unsigned int)f2bf(a) | ((unsigned int)f2bf(c2) << 16);
        }
        unsigned short* xtr = xT + ((size_t)b * NTOK + n0 + n) * CCH + c0;
        *(uint4*)(xtr)     = *(uint4*)(pk);
        *(uint4*)(xtr + 8) = *(uint4*)(pk + 4);
        const int g0 = c0 >> 3;
        *(uint4*)(Xb + (n << 6) + ((g0 ^ (n & 7)) << 3))       = *(uint4*)(pk);
        *(uint4*)(Xb + (n << 6) + (((g0 + 1) ^ (n & 7)) << 3)) = *(uint4*)(pk + 4);
    }
    __syncthreads();

    // ---- phase C: support via MFMA; wave wv owns n-subtile wv ----
    v8bf aw0[4], aw1[4];
    #pragma unroll
    for (int dt = 0; dt < 4; ++dt) {
        #pragma unroll
        for (int j = 0; j < 8; ++j) {
            aw0[dt][j] = (__bf16)w[(quad * 8 + j) * 64 + dt * 16 + l16];
            aw1[dt][j] = (__bf16)w[(quad * 8 + j + 32) * 64 + dt * 16 + l16];
        }
    }
    const int nrow = wv * 16 + l16;
    const unsigned short* xr = Xb + (nrow << 6);
    const int cc = quad ^ (nrow & 7);
    const v8bf bx0 = ld8(xr + (cc << 3));
    const v8bf bx1 = ld8(xr + ((cc ^ 4) << 3));

    unsigned short* stb = sT + (size_t)b * CCH * NTOK + n0 + wv * 16 + l16;
    #pragma unroll
    for (int dt = 0; dt < 4; ++dt) {
        v4f z; z[0]=0.f; z[1]=0.f; z[2]=0.f; z[3]=0.f;
        z = __builtin_amdgcn_mfma_f32_16x16x32_bf16(aw0[dt], bx0, z, 0, 0, 0);
        z = __builtin_amdgcn_mfma_f32_16x16x32_bf16(aw1[dt], bx1, z, 0, 0, 0);
        #pragma unroll
        for (int r = 0; r < 4; ++r)
            stb[(size_t)(dt * 16 + quad * 4 + r) * NTOK] = f2bf(z[r]);
    }
}

// ---------------------------------------------------------------------------
// Flash chunk kernel, barrier-free. Grid: (32 i-tiles, KS, 8 b) x 256 thr.
// Block = 128 Q rows (32/wave = 2 m-tiles). K/V fragments read DIRECTLY from
// global (xT/sT are L1/L2-hot; 16x64B segments per b128 load). LDS = only the
// wave-private P^T round-trip. No __syncthreads anywhere.
// S^T = K·Q^T: D[row=j_loc=quad*4+r][col=i_loc=l16]. P^T in LDS [i][j]
// (stride 64, chunk^(i&7)). O^T = V^T·P^T. l via mfma(ones, P^T).
// ---------------------------------------------------------------------------
__global__ __launch_bounds__(256, 6) void flash_kernel(
    const unsigned short* __restrict__ xT,   // [8][4096][64]
    const unsigned short* __restrict__ sT,   // [8][64][4096]
    float* __restrict__ part_o,              // [8][KS][4096][64]
    float* __restrict__ part_l,              // [8][KS][4096]
    int nchunk, int chunk_len)
{
    __shared__ __align__(16) unsigned short Pt[4][32 * 64];  // 16 KB total

    const int tid  = threadIdx.x;
    const int w    = tid >> 6;
    const int lane = tid & 63;
    const int quad = lane >> 4;
    const int l16  = lane & 15;
    const int l7   = l16 & 7;
    const int b     = blockIdx.z;
    const int chunk = blockIdx.y;
    const int i0   = blockIdx.x * 128;
    const int irow = i0 + w * 32;
    const int jb   = chunk * chunk_len;

    const unsigned short* xTb = xT + (size_t)b * NTOK * CCH;
    const unsigned short* sTb = sT + (size_t)b * CCH * NTOK;

    // Q fragments (B-operand of S^T)
    v8bf aq0[2], aq1[2];
    #pragma unroll
    for (int m = 0; m < 2; ++m) {
        const unsigned short* qr = xTb + (size_t)(irow + m * 16 + l16) * CCH + quad * 8;
        aq0[m] = ld8(qr);
        aq1[m] = ld8(qr + 32);
    }

    // fixed stabilizer pre-scaled: negml2[m] = -||q_i||^2 * log2(e)
    float negml2[2];
    #pragma unroll
    for (int m = 0; m < 2; ++m) {
        float msq = 0.f;
        #pragma unroll
        for (int i = 0; i < 8; ++i) {
            float e0 = (float)aq0[m][i], e1 = (float)aq1[m][i];
            msq = fmaf(e0, e0, msq);
            msq = fmaf(e1, e1, msq);
        }
        msq += __shfl_xor(msq, 16);
        msq += __shfl_xor(msq, 32);
        negml2[m] = -msq * LOG2E;
    }

    v8bf ones;
    #pragma unroll
    for (int i = 0; i < 8; ++i) ones[i] = (__bf16)1.0f;

    v4f o[2][4];
    v4f lsum[2];
    #pragma unroll
    for (int m = 0; m < 2; ++m) {
        lsum[m][0]=0.f; lsum[m][1]=0.f; lsum[m][2]=0.f; lsum[m][3]=0.f;
        #pragma unroll
        for (int ct = 0; ct < 4; ++ct) { o[m][ct][0]=0.f; o[m][ct][1]=0.f; o[m][ct][2]=0.f; o[m][ct][3]=0.f; }
    }

    unsigned short* Pw = Pt[w];
    const int phalf = (quad & 1) * 4;
    const int pgq   = quad >> 1;

    for (int jj = 0; jj < chunk_len; jj += 64) {
        const int j0 = jb + jj;

        // ---- S^T = K Q^T (K frags straight from L1/L2), exp2, store P^T ----
        #pragma unroll
        for (int jt = 0; jt < 4; ++jt) {
            const unsigned short* kr = xTb + (size_t)(j0 + 16 * jt + l16) * CCH + quad * 8;
            v8bf bk0 = ld8(kr);
            v8bf bk1 = ld8(kr + 32);
            #pragma unroll
            for (int m = 0; m < 2; ++m) {
                v4f z; z[0]=0.f; z[1]=0.f; z[2]=0.f; z[3]=0.f;
                z = __builtin_amdgcn_mfma_f32_16x16x32_bf16(bk0, aq0[m], z, 0, 0, 0);
                z = __builtin_amdgcn_mfma_f32_16x16x32_bf16(bk1, aq1[m], z, 0, 0, 0);
                const float p0 = exp2f(fmaf(z[0], LOG2E, negml2[m]));
                const float p1 = exp2f(fmaf(z[1], LOG2E, negml2[m]));
                const float p2 = exp2f(fmaf(z[2], LOG2E, negml2[m]));
                const float p3 = exp2f(fmaf(z[3], LOG2E, negml2[m]));
                uint2 pk; pk.x = pkbf(p0, p1); pk.y = pkbf(p2, p3);
                const int pos = (2 * jt + pgq) ^ l7;
                *(uint2*)(Pw + (m * 16 + l16) * 64 + pos * 8 + phalf) = pk;
            }
        }

        // ---- P^T B-frags (wave-local; lgkmcnt ordering only) + MFMA sums ----
        v8bf pb0[2], pb1[2];
        #pragma unroll
        for (int m = 0; m < 2; ++m) {
            const unsigned short* pr = Pw + (m * 16 + l16) * 64;
            const int p0c = quad ^ l7;
            pb0[m] = ld8(pr + p0c * 8);
            pb1[m] = ld8(pr + (p0c ^ 4) * 8);
            lsum[m] = __builtin_amdgcn_mfma_f32_16x16x32_bf16(ones, pb0[m], lsum[m], 0, 0, 0);
            lsum[m] = __builtin_amdgcn_mfma_f32_16x16x32_bf16(ones, pb1[m], lsum[m], 0, 0, 0);
        }

        // ---- O^T += V^T P^T (V frags straight from L1/L2) ----
        #pragma unroll
        for (int ct = 0; ct < 4; ++ct) {
            const unsigned short* vr = sTb + (size_t)(16 * ct + l16) * NTOK + j0 + quad * 8;
            v8bf bv0 = ld8(vr);
            v8bf bv1 = ld8(vr + 32);
            #pragma unroll
            for (int m = 0; m < 2; ++m) {
                o[m][ct] = __builtin_amdgcn_mfma_f32_16x16x32_bf16(bv0, pb0[m], o[m][ct], 0, 0, 0);
                o[m][ct] = __builtin_amdgcn_mfma_f32_16x16x32_bf16(bv1, pb1[m], o[m][ct], 0, 0, 0);
            }
        }
    }

    // ---- epilogue ----
    const size_t pbase = (size_t)(b * nchunk + chunk) * NTOK + irow;
    #pragma unroll
    for (int m = 0; m < 2; ++m)
        if (quad == 0) part_l[pbase + m * 16 + l16] = lsum[m][0];
    float* po = part_o + pbase * 64;
    #pragma unroll
    for (int m = 0; m < 2; ++m)
        #pragma unroll
        for (int ct = 0; ct < 4; ++ct)
            *(v4f*)(po + (size_t)(m * 16 + l16) * 64 + ct * 16 + quad * 4) = o[m][ct];
}

// ---------------------------------------------------------------------------
// Combine: sum chunk partials, normalize, transpose, add x, store.
// Grid: (128 i-tiles of 32 rows, 8 batches) x 256 threads. KS compile-time.
// ---------------------------------------------------------------------------
template <int KS_>
__global__ __launch_bounds__(256) void combine_kernel(
    const float* __restrict__ part_o,  // [8][KS][4096][64]
    const float* __restrict__ part_l,  // [8][KS][4096]
    const float* __restrict__ x,       // [8][64][4096]
    float* __restrict__ out)           // [8][64][4096]
{
    __shared__ float Of[32 * 65];
    const int tid = threadIdx.x;
    const int b = blockIdx.y;
    const int i0 = blockIdx.x * 32;

    const int row = tid >> 3;          // 0..31
    const int col = (tid & 7) * 8;
    float acc[8];
    #pragma unroll
    for (int k = 0; k < 8; ++k) acc[k] = 0.f;
    float lt = 0.f;

    #pragma unroll
    for (int ch = 0; ch < KS_; ++ch) {
        const size_t base = (size_t)(b * KS_ + ch) * NTOK + i0 + row;
        lt += part_l[base];
        const float* po = part_o + base * 64 + col;
        float4 v0 = *(const float4*)(po);
        float4 v1 = *(const float4*)(po + 4);
        acc[0]+=v0.x; acc[1]+=v0.y; acc[2]+=v0.z; acc[3]+=v0.w;
        acc[4]+=v1.x; acc[5]+=v1.y; acc[6]+=v1.z; acc[7]+=v1.w;
    }
    const float inv = 1.f / lt;
    #pragma unroll
    for (int k = 0; k < 8; ++k) Of[row * 65 + col + k] = acc[k] * inv;
    __syncthreads();

    const int c    = tid >> 2;
    const int part = tid & 3;
    const float* xrow = x   + ((size_t)b * CCH + c) * NTOK + i0 + part * 8;
    float*       orow = out + ((size_t)b * CCH + c) * NTOK + i0 + part * 8;
    #pragma unroll
    for (int i4 = 0; i4 < 2; ++i4) {
        float4 xv = *(const float4*)(xrow + i4 * 4);
        float4 ov;
        ov.x = Of[(part * 8 + i4 * 4 + 0) * 65 + c] + xv.x;
        ov.y = Of[(part * 8 + i4 * 4 + 1) * 65 + c] + xv.y;
        ov.z = Of[(part * 8 + i4 * 4 + 2) * 65 + c] + xv.z;
        ov.w = Of[(part * 8 + i4 * 4 + 3) * 65 + c] + xv.w;
        *(float4*)(orow + i4 * 4) = ov;
    }
}

// ---------------------------------------------------------------------------
extern "C" void kernel_launch(void* const* d_in, const int* in_sizes, int n_in,
                              void* d_out, int out_size, void* d_ws, size_t ws_size,
                              hipStream_t stream) {
    const float* x = (const float*)d_in[0];
    const float* w = (const float*)d_in[1];
    float* out = (float*)d_out;

    const size_t xT_elems = (size_t)8 * NTOK * CCH;         // 2M shorts = 4 MB
    unsigned short* xT = (unsigned short*)d_ws;
    unsigned short* sT = xT + xT_elems;
    char* rest = (char*)d_ws + 2 * xT_elems * sizeof(unsigned short);   // +8 MB

    int KS = 8;
    while (KS > 1) {
        size_t need = 2 * xT_elems * sizeof(unsigned short)
                    + (size_t)KS * ((size_t)8 * NTOK * CCH * 4 + (size_t)8 * NTOK * 4);
        if (need <= ws_size) break;
        KS >>= 1;
    }
    float* part_o = (float*)rest;
    float* part_l = (float*)(rest + (size_t)KS * 8 * NTOK * CCH * 4);

    dim3 gp(64, 8);
    prep_kernel<<<gp, 256, 0, stream>>>(x, w, xT, sT);
    dim3 gf(32, KS, 8);
    flash_kernel<<<gf, 256, 0, stream>>>(xT, sT, part_o, part_l, KS, NTOK / KS);
    dim3 gc(128, 8);
    if (KS == 8)      combine_kernel<8><<<gc, 256, 0, stream>>>(part_o, part_l, x, out);
    else if (KS == 4) combine_kernel<4><<<gc, 256, 0, stream>>>(part_o, part_l, x, out);
    else if (KS == 2) combine_kernel<2><<<gc, 256, 0, stream>>>(part_o, part_l, x, out);
    else              combine_kernel<1><<<gc, 256, 0, stream>>>(part_o, part_l, x, out);
}

// Round 9
// 193.261 us; speedup vs baseline: 1.3628x; 1.3628x over previous
//
#include <hip/hip_runtime.h>
#include <stdint.h>

// B=8, C=64, N=4096. Flash attention with Q=K=x^T [N,64], V=x^T W [N,64].
// Round 9: R8 barrier-free/direct-global flash, RETESTED with the register
// cap removed. R8's 195-305us was pure scratch-spill (VGPR=40 from
// launch_bounds(256,6); FETCH 145MB phantom). Rule: min-waves>=4 caps VGPR
// below the ~90-reg working set -> spill. Here: launch_bounds(256) (natural
// allocation), KS=4 (R7: KS=8 costs +6us overhead + 2x combine traffic).
// K/V frags stream from L1/L2 (xT/sT = 8MB, L2-resident), LDS only holds the
// wave-private P^T round-trip, zero __syncthreads in the K-loop.

#define NTOK 4096
#define CCH  64
#define LOG2E 1.44269504088896340736f

typedef float v4f __attribute__((ext_vector_type(4)));
typedef __bf16 v8bf __attribute__((ext_vector_type(8)));
typedef unsigned short v8us __attribute__((ext_vector_type(8)));

__device__ __forceinline__ unsigned short f2bf(float f) {
    union { float f; unsigned int u; } c; c.f = f;
    unsigned int r = c.u + 0x7fffu + ((c.u >> 16) & 1u);   // RNE
    return (unsigned short)(r >> 16);
}

__device__ __forceinline__ v8bf ld8(const unsigned short* p) {
    union { v8us s; v8bf b; } u;
    u.s = *(const v8us*)p;
    return u.b;
}

// pack two f32 -> u32 of (bf16_trunc(a) | bf16_trunc(b)<<16), one v_perm
__device__ __forceinline__ unsigned int pkbf(float a, float b) {
    union { float f; unsigned int u; } ua, ub; ua.f = a; ub.f = b;
    return __builtin_amdgcn_perm(ub.u, ua.u, 0x07060302u);
}

// ---------------------------------------------------------------------------
// Prep: xT[b][n][c] = bf16(x[b][c][n]);  sT[b][d][n] = bf16(sum_c x[b][c][n] W[c][d])
// Grid (64, 8) x 256. Support via MFMA (A=W^T frags, B=x bf16 tile from LDS).
// ---------------------------------------------------------------------------
__global__ __launch_bounds__(256) void prep_kernel(
    const float* __restrict__ x,        // [8][64][4096]
    const float* __restrict__ w,        // [64][64]
    unsigned short* __restrict__ xT,    // [8][4096][64] bf16
    unsigned short* __restrict__ sT)    // [8][64][4096] bf16
{
    __shared__ float Xf[64 * 65];                        // [c][n] f32, stride 65
    __shared__ __align__(16) unsigned short Xb[64 * 64]; // [n][c] bf16, swizzled

    const int tid  = threadIdx.x;
    const int lane = tid & 63;
    const int wv   = __builtin_amdgcn_readfirstlane(tid >> 6);
    const int quad = lane >> 4;
    const int l16  = lane & 15;
    const int b    = blockIdx.y;
    const int n0   = blockIdx.x * 64;

    // ---- phase A: stage x tile [64 c][64 n] f32 into LDS (coalesced) ----
    const float* xb = x + (size_t)b * CCH * NTOK + n0 + lane;
    #pragma unroll
    for (int k = 0; k < 16; ++k) {
        const int c = wv * 16 + k;
        Xf[c * 65 + lane] = xb[(size_t)c * NTOK];
    }
    __syncthreads();

    // ---- phase B: pack bf16 row fragments; write xT (global) + Xb (LDS) ----
    {
        const int n  = tid >> 2;
        const int c0 = (tid & 3) * 16;
        unsigned int pk[8];
        #pragma unroll
        for (int k = 0; k < 8; ++k) {
            const float a  = Xf[(c0 + 2 * k) * 65 + n];
            const float c2 = Xf[(c0 + 2 * k + 1) * 65 + n];
            pk[k] = (unsigned int)f2bf(a) | ((unsigned int)f2bf(c2) << 16);
        }
        unsigned short* xtr = xT + ((size_t)b * NTOK + n0 + n) * CCH + c0;
        *(uint4*)(xtr)     = *(uint4*)(pk);
        *(uint4*)(xtr + 8) = *(uint4*)(pk + 4);
        const int g0 = c0 >> 3;
        *(uint4*)(Xb + (n << 6) + ((g0 ^ (n & 7)) << 3))       = *(uint4*)(pk);
        *(uint4*)(Xb + (n << 6) + (((g0 + 1) ^ (n & 7)) << 3)) = *(uint4*)(pk + 4);
    }
    __syncthreads();

    // ---- phase C: support via MFMA; wave wv owns n-subtile wv ----
    v8bf aw0[4], aw1[4];
    #pragma unroll
    for (int dt = 0; dt < 4; ++dt) {
        #pragma unroll
        for (int j = 0; j < 8; ++j) {
            aw0[dt][j] = (__bf16)w[(quad * 8 + j) * 64 + dt * 16 + l16];
            aw1[dt][j] = (__bf16)w[(quad * 8 + j + 32) * 64 + dt * 16 + l16];
        }
    }
    const int nrow = wv * 16 + l16;
    const unsigned short* xr = Xb + (nrow << 6);
    const int cc = quad ^ (nrow & 7);
    const v8bf bx0 = ld8(xr + (cc << 3));
    const v8bf bx1 = ld8(xr + ((cc ^ 4) << 3));

    unsigned short* stb = sT + (size_t)b * CCH * NTOK + n0 + wv * 16 + l16;
    #pragma unroll
    for (int dt = 0; dt < 4; ++dt) {
        v4f z; z[0]=0.f; z[1]=0.f; z[2]=0.f; z[3]=0.f;
        z = __builtin_amdgcn_mfma_f32_16x16x32_bf16(aw0[dt], bx0, z, 0, 0, 0);
        z = __builtin_amdgcn_mfma_f32_16x16x32_bf16(aw1[dt], bx1, z, 0, 0, 0);
        #pragma unroll
        for (int r = 0; r < 4; ++r)
            stb[(size_t)(dt * 16 + quad * 4 + r) * NTOK] = f2bf(z[r]);
    }
}

// ---------------------------------------------------------------------------
// Flash chunk kernel, barrier-free. Grid: (32 i-tiles, KS, 8 b) x 256 thr.
// Block = 128 Q rows (32/wave = 2 m-tiles). K/V fragments read DIRECTLY from
// global (xT/sT L2-resident). LDS = wave-private P^T round-trip only.
// S^T = K·Q^T: D[row=j_loc=quad*4+r][col=i_loc=l16]. P^T in LDS [i][j]
// (stride 64, chunk^(i&7)). O^T = V^T·P^T. l via mfma(ones, P^T).
// NO launch_bounds min-waves: caps <=4 proven to spill (R2: 40 VGPR, R8: 40).
// ---------------------------------------------------------------------------
__global__ __launch_bounds__(256) void flash_kernel(
    const unsigned short* __restrict__ xT,   // [8][4096][64]
    const unsigned short* __restrict__ sT,   // [8][64][4096]
    float* __restrict__ part_o,              // [8][KS][4096][64]
    float* __restrict__ part_l,              // [8][KS][4096]
    int nchunk, int chunk_len)
{
    __shared__ __align__(16) unsigned short Pt[4][32 * 64];  // 16 KB total

    const int tid  = threadIdx.x;
    const int w    = tid >> 6;
    const int lane = tid & 63;
    const int quad = lane >> 4;
    const int l16  = lane & 15;
    const int l7   = l16 & 7;
    const int b     = blockIdx.z;
    const int chunk = blockIdx.y;
    const int i0   = blockIdx.x * 128;
    const int irow = i0 + w * 32;
    const int jb   = chunk * chunk_len;

    const unsigned short* xTb = xT + (size_t)b * NTOK * CCH;
    const unsigned short* sTb = sT + (size_t)b * CCH * NTOK;

    // Q fragments (B-operand of S^T)
    v8bf aq0[2], aq1[2];
    #pragma unroll
    for (int m = 0; m < 2; ++m) {
        const unsigned short* qr = xTb + (size_t)(irow + m * 16 + l16) * CCH + quad * 8;
        aq0[m] = ld8(qr);
        aq1[m] = ld8(qr + 32);
    }

    // fixed stabilizer pre-scaled: negml2[m] = -||q_i||^2 * log2(e)
    float negml2[2];
    #pragma unroll
    for (int m = 0; m < 2; ++m) {
        float msq = 0.f;
        #pragma unroll
        for (int i = 0; i < 8; ++i) {
            float e0 = (float)aq0[m][i], e1 = (float)aq1[m][i];
            msq = fmaf(e0, e0, msq);
            msq = fmaf(e1, e1, msq);
        }
        msq += __shfl_xor(msq, 16);
        msq += __shfl_xor(msq, 32);
        negml2[m] = -msq * LOG2E;
    }

    v8bf ones;
    #pragma unroll
    for (int i = 0; i < 8; ++i) ones[i] = (__bf16)1.0f;

    v4f o[2][4];
    v4f lsum[2];
    #pragma unroll
    for (int m = 0; m < 2; ++m) {
        lsum[m][0]=0.f; lsum[m][1]=0.f; lsum[m][2]=0.f; lsum[m][3]=0.f;
        #pragma unroll
        for (int ct = 0; ct < 4; ++ct) { o[m][ct][0]=0.f; o[m][ct][1]=0.f; o[m][ct][2]=0.f; o[m][ct][3]=0.f; }
    }

    unsigned short* Pw = Pt[w];
    const int phalf = (quad & 1) * 4;
    const int pgq   = quad >> 1;

    for (int jj = 0; jj < chunk_len; jj += 64) {
        const int j0 = jb + jj;

        // ---- S^T = K Q^T (K frags straight from L1/L2), exp2, store P^T ----
        #pragma unroll
        for (int jt = 0; jt < 4; ++jt) {
            const unsigned short* kr = xTb + (size_t)(j0 + 16 * jt + l16) * CCH + quad * 8;
            v8bf bk0 = ld8(kr);
            v8bf bk1 = ld8(kr + 32);
            #pragma unroll
            for (int m = 0; m < 2; ++m) {
                v4f z; z[0]=0.f; z[1]=0.f; z[2]=0.f; z[3]=0.f;
                z = __builtin_amdgcn_mfma_f32_16x16x32_bf16(bk0, aq0[m], z, 0, 0, 0);
                z = __builtin_amdgcn_mfma_f32_16x16x32_bf16(bk1, aq1[m], z, 0, 0, 0);
                const float p0 = exp2f(fmaf(z[0], LOG2E, negml2[m]));
                const float p1 = exp2f(fmaf(z[1], LOG2E, negml2[m]));
                const float p2 = exp2f(fmaf(z[2], LOG2E, negml2[m]));
                const float p3 = exp2f(fmaf(z[3], LOG2E, negml2[m]));
                uint2 pk; pk.x = pkbf(p0, p1); pk.y = pkbf(p2, p3);
                const int pos = (2 * jt + pgq) ^ l7;
                *(uint2*)(Pw + (m * 16 + l16) * 64 + pos * 8 + phalf) = pk;
            }
        }

        // ---- P^T B-frags (wave-local; lgkmcnt ordering only) + MFMA sums ----
        v8bf pb0[2], pb1[2];
        #pragma unroll
        for (int m = 0; m < 2; ++m) {
            const unsigned short* pr = Pw + (m * 16 + l16) * 64;
            const int p0c = quad ^ l7;
            pb0[m] = ld8(pr + p0c * 8);
            pb1[m] = ld8(pr + (p0c ^ 4) * 8);
            lsum[m] = __builtin_amdgcn_mfma_f32_16x16x32_bf16(ones, pb0[m], lsum[m], 0, 0, 0);
            lsum[m] = __builtin_amdgcn_mfma_f32_16x16x32_bf16(ones, pb1[m], lsum[m], 0, 0, 0);
        }

        // ---- O^T += V^T P^T (V frags straight from L1/L2) ----
        #pragma unroll
        for (int ct = 0; ct < 4; ++ct) {
            const unsigned short* vr = sTb + (size_t)(16 * ct + l16) * NTOK + j0 + quad * 8;
            v8bf bv0 = ld8(vr);
            v8bf bv1 = ld8(vr + 32);
            #pragma unroll
            for (int m = 0; m < 2; ++m) {
                o[m][ct] = __builtin_amdgcn_mfma_f32_16x16x32_bf16(bv0, pb0[m], o[m][ct], 0, 0, 0);
                o[m][ct] = __builtin_amdgcn_mfma_f32_16x16x32_bf16(bv1, pb1[m], o[m][ct], 0, 0, 0);
            }
        }
    }

    // ---- epilogue ----
    const size_t pbase = (size_t)(b * nchunk + chunk) * NTOK + irow;
    #pragma unroll
    for (int m = 0; m < 2; ++m)
        if (quad == 0) part_l[pbase + m * 16 + l16] = lsum[m][0];
    float* po = part_o + pbase * 64;
    #pragma unroll
    for (int m = 0; m < 2; ++m)
        #pragma unroll
        for (int ct = 0; ct < 4; ++ct)
            *(v4f*)(po + (size_t)(m * 16 + l16) * 64 + ct * 16 + quad * 4) = o[m][ct];
}

// ---------------------------------------------------------------------------
// Combine: sum chunk partials, normalize, transpose, add x, store.
// Grid: (128 i-tiles of 32 rows, 8 batches) x 256 threads. KS compile-time.
// ---------------------------------------------------------------------------
template <int KS_>
__global__ __launch_bounds__(256) void combine_kernel(
    const float* __restrict__ part_o,  // [8][KS][4096][64]
    const float* __restrict__ part_l,  // [8][KS][4096]
    const float* __restrict__ x,       // [8][64][4096]
    float* __restrict__ out)           // [8][64][4096]
{
    __shared__ float Of[32 * 65];
    const int tid = threadIdx.x;
    const int b = blockIdx.y;
    const int i0 = blockIdx.x * 32;

    const int row = tid >> 3;          // 0..31
    const int col = (tid & 7) * 8;
    float acc[8];
    #pragma unroll
    for (int k = 0; k < 8; ++k) acc[k] = 0.f;
    float lt = 0.f;

    #pragma unroll
    for (int ch = 0; ch < KS_; ++ch) {
        const size_t base = (size_t)(b * KS_ + ch) * NTOK + i0 + row;
        lt += part_l[base];
        const float* po = part_o + base * 64 + col;
        float4 v0 = *(const float4*)(po);
        float4 v1 = *(const float4*)(po + 4);
        acc[0]+=v0.x; acc[1]+=v0.y; acc[2]+=v0.z; acc[3]+=v0.w;
        acc[4]+=v1.x; acc[5]+=v1.y; acc[6]+=v1.z; acc[7]+=v1.w;
    }
    const float inv = 1.f / lt;
    #pragma unroll
    for (int k = 0; k < 8; ++k) Of[row * 65 + col + k] = acc[k] * inv;
    __syncthreads();

    const int c    = tid >> 2;
    const int part = tid & 3;
    const float* xrow = x   + ((size_t)b * CCH + c) * NTOK + i0 + part * 8;
    float*       orow = out + ((size_t)b * CCH + c) * NTOK + i0 + part * 8;
    #pragma unroll
    for (int i4 = 0; i4 < 2; ++i4) {
        float4 xv = *(const float4*)(xrow + i4 * 4);
        float4 ov;
        ov.x = Of[(part * 8 + i4 * 4 + 0) * 65 + c] + xv.x;
        ov.y = Of[(part * 8 + i4 * 4 + 1) * 65 + c] + xv.y;
        ov.z = Of[(part * 8 + i4 * 4 + 2) * 65 + c] + xv.z;
        ov.w = Of[(part * 8 + i4 * 4 + 3) * 65 + c] + xv.w;
        *(float4*)(orow + i4 * 4) = ov;
    }
}

// ---------------------------------------------------------------------------
extern "C" void kernel_launch(void* const* d_in, const int* in_sizes, int n_in,
                              void* d_out, int out_size, void* d_ws, size_t ws_size,
                              hipStream_t stream) {
    const float* x = (const float*)d_in[0];
    const float* w = (const float*)d_in[1];
    float* out = (float*)d_out;

    const size_t xT_elems = (size_t)8 * NTOK * CCH;         // 2M shorts = 4 MB
    unsigned short* xT = (unsigned short*)d_ws;
    unsigned short* sT = xT + xT_elems;
    char* rest = (char*)d_ws + 2 * xT_elems * sizeof(unsigned short);   // +8 MB

    int KS = 4;
    while (KS > 1) {
        size_t need = 2 * xT_elems * sizeof(unsigned short)
                    + (size_t)KS * ((size_t)8 * NTOK * CCH * 4 + (size_t)8 * NTOK * 4);
        if (need <= ws_size) break;
        KS >>= 1;
    }
    float* part_o = (float*)rest;
    float* part_l = (float*)(rest + (size_t)KS * 8 * NTOK * CCH * 4);

    dim3 gp(64, 8);
    prep_kernel<<<gp, 256, 0, stream>>>(x, w, xT, sT);
    dim3 gf(32, KS, 8);
    flash_kernel<<<gf, 256, 0, stream>>>(xT, sT, part_o, part_l, KS, NTOK / KS);
    dim3 gc(128, 8);
    if (KS == 4)      combine_kernel<4><<<gc, 256, 0, stream>>>(part_o, part_l, x, out);
    else if (KS == 2) combine_kernel<2><<<gc, 256, 0, stream>>>(part_o, part_l, x, out);
    else              combine_kernel<1><<<gc, 256, 0, stream>>>(part_o, part_l, x, out);
}

// Round 10
// 135.531 us; speedup vs baseline: 1.9432x; 1.4260x over previous
//
#include <hip/hip_runtime.h>
#include <stdint.h>

// B=8, C=64, N=4096. Flash attention with Q=K=x^T [N,64], V=x^T W [N,64].
// Round 10: FRAGMENT-MAJOR direct-global flash. R9 proved direct-global fails
// only because element-major layouts make fragment loads a 32-segment gather.
// Prep now emits kf/vf: for each 16-token tile, the exact 16B-per-lane MFMA
// fragment bytes at (base + lane*16) -> every flash K/V load is ONE coalesced
// 1KB dwordx4 from L1/L2 (xT/sT deleted). No K/V LDS, no __syncthreads in
// flash; LDS = wave-private P^T round-trip only (16 KB). Compiler can
// software-pipeline loads across K-iters (no barrier fences).
// kf[b][t16][h][lane*8]: x[c=quad*8+h*32+jj][n=16*t16+l16]   (A-frag of K,
//   ALSO the B-frag of Q^T -> Q prologue reads kf too).
// vf[b][j64][ct][h][lane*8]: support[d=16ct+l16][tok=j64*64+h*32+quad*8+jj].

#define NTOK 4096
#define CCH  64
#define LOG2E 1.44269504088896340736f

typedef float v4f __attribute__((ext_vector_type(4)));
typedef __bf16 v8bf __attribute__((ext_vector_type(8)));
typedef unsigned short v8us __attribute__((ext_vector_type(8)));

__device__ __forceinline__ unsigned short f2bf(float f) {
    union { float f; unsigned int u; } c; c.f = f;
    unsigned int r = c.u + 0x7fffu + ((c.u >> 16) & 1u);   // RNE
    return (unsigned short)(r >> 16);
}

__device__ __forceinline__ v8bf ld8(const unsigned short* p) {
    union { v8us s; v8bf b; } u;
    u.s = *(const v8us*)p;
    return u.b;
}

// pack two f32 -> u32 of (bf16_trunc(a) | bf16_trunc(b)<<16), one v_perm
__device__ __forceinline__ unsigned int pkbf(float a, float b) {
    union { float f; unsigned int u; } ua, ub; ua.f = a; ub.f = b;
    return __builtin_amdgcn_perm(ub.u, ua.u, 0x07060302u);
}

// ---------------------------------------------------------------------------
// Prep. Grid (64, 8) x 256. Block = 64 tokens (= one j64 block, four t16).
// A: stage x f32 tile. B: pack bf16 n-major Xb (swizzled). B2: emit kf.
// C: support = W^T x via MFMA -> St (LDS, d-major, swizzled). D: emit vf.
// ---------------------------------------------------------------------------
__global__ __launch_bounds__(256) void prep_kernel(
    const float* __restrict__ x,        // [8][64][4096]
    const float* __restrict__ w,        // [64][64]
    unsigned short* __restrict__ kf,    // [8][256][2][512]
    unsigned short* __restrict__ vf)    // [8][64][4][2][512]
{
    __shared__ float Xf[64 * 65];                        // [c][n] f32
    __shared__ __align__(16) unsigned short Xb[64 * 64]; // [n][c] bf16 swizzled
    __shared__ __align__(16) unsigned short St[64 * 64]; // [d][n] bf16 swizzled

    const int tid  = threadIdx.x;
    const int lane = tid & 63;
    const int wv   = __builtin_amdgcn_readfirstlane(tid >> 6);
    const int quad = lane >> 4;
    const int l16  = lane & 15;
    const int b    = blockIdx.y;
    const int n0   = blockIdx.x * 64;

    // ---- phase A: stage x tile [64 c][64 n] f32 (coalesced) ----
    const float* xb = x + (size_t)b * CCH * NTOK + n0 + lane;
    #pragma unroll
    for (int k = 0; k < 16; ++k) {
        const int c = wv * 16 + k;
        Xf[c * 65 + lane] = xb[(size_t)c * NTOK];
    }
    __syncthreads();

    // ---- phase B: pack bf16 rows into Xb (n-major, chunk pos g^(n&7)) ----
    {
        const int n  = tid >> 2;
        const int c0 = (tid & 3) * 16;
        unsigned int pk[8];
        #pragma unroll
        for (int k = 0; k < 8; ++k) {
            const float a  = Xf[(c0 + 2 * k) * 65 + n];
            const float c2 = Xf[(c0 + 2 * k + 1) * 65 + n];
            pk[k] = (unsigned int)f2bf(a) | ((unsigned int)f2bf(c2) << 16);
        }
        const int g0 = c0 >> 3;
        *(uint4*)(Xb + (n << 6) + ((g0 ^ (n & 7)) << 3))       = *(uint4*)(pk);
        *(uint4*)(Xb + (n << 6) + (((g0 + 1) ^ (n & 7)) << 3)) = *(uint4*)(pk + 4);
    }
    __syncthreads();

    // ---- phase B2: emit kf (coalesced 1KB stores) ----
    {
        const int t16 = tid >> 6;                 // local tile 0..3
        const int nr  = 16 * t16 + l16;           // local token row
        unsigned short* kfo = kf + ((size_t)b * 256 + (n0 >> 4) + t16) * 1024 + lane * 8;
        #pragma unroll
        for (int h = 0; h < 2; ++h) {
            const int g = (quad + 4 * h) ^ (nr & 7);
            *(v8us*)(kfo + h * 512) = *(const v8us*)(Xb + (nr << 6) + (g << 3));
        }
    }

    // ---- phase C: support via MFMA -> St (d-major, chunk pos g^(d&7)) ----
    {
        v8bf aw0[4], aw1[4];
        #pragma unroll
        for (int dt = 0; dt < 4; ++dt) {
            #pragma unroll
            for (int j = 0; j < 8; ++j) {
                aw0[dt][j] = (__bf16)w[(quad * 8 + j) * 64 + dt * 16 + l16];
                aw1[dt][j] = (__bf16)w[(quad * 8 + j + 32) * 64 + dt * 16 + l16];
            }
        }
        const int nrow = wv * 16 + l16;
        const unsigned short* xr = Xb + (nrow << 6);
        const int cc = quad ^ (nrow & 7);
        const v8bf bx0 = ld8(xr + (cc << 3));
        const v8bf bx1 = ld8(xr + ((cc ^ 4) << 3));

        const int nchunk_lo = (nrow >> 3);        // chunk index of this n
        #pragma unroll
        for (int dt = 0; dt < 4; ++dt) {
            v4f z; z[0]=0.f; z[1]=0.f; z[2]=0.f; z[3]=0.f;
            z = __builtin_amdgcn_mfma_f32_16x16x32_bf16(aw0[dt], bx0, z, 0, 0, 0);
            z = __builtin_amdgcn_mfma_f32_16x16x32_bf16(aw1[dt], bx1, z, 0, 0, 0);
            #pragma unroll
            for (int r = 0; r < 4; ++r) {
                const int d = dt * 16 + quad * 4 + r;
                St[(d << 6) + ((nchunk_lo ^ (d & 7)) << 3) + (nrow & 7)] = f2bf(z[r]);
            }
        }
    }
    __syncthreads();

    // ---- phase D: emit vf (coalesced 1KB stores) ----
    {
        const int ct = tid >> 6;                  // d-tile 0..3
        const int d  = 16 * ct + l16;
        unsigned short* vfo = vf + (((size_t)b * 64 + blockIdx.x) * 4 + ct) * 1024 + lane * 8;
        #pragma unroll
        for (int h = 0; h < 2; ++h) {
            const int g = (quad + 4 * h) ^ (d & 7);
            *(v8us*)(vfo + h * 512) = *(const v8us*)(St + (d << 6) + (g << 3));
        }
    }
}

// ---------------------------------------------------------------------------
// Flash chunk kernel, barrier-free, fragment-major. Grid: (32, KS, 8) x 256.
// Block = 128 Q rows (32/wave = 2 m-tiles). All K/V loads coalesced dwordx4
// from kf/vf (L1/L2-hot). LDS = wave-private P^T round-trip only.
// S^T = K·Q^T: D[row=j_loc=quad*4+r][col=i_loc=l16]. O^T = V^T·P^T.
// NO launch_bounds min-waves (caps spill: R2/R8 postmortems).
// ---------------------------------------------------------------------------
__global__ __launch_bounds__(256) void flash_kernel(
    const unsigned short* __restrict__ kf,   // [8][256][2][512]
    const unsigned short* __restrict__ vf,   // [8][64][4][2][512]
    float* __restrict__ part_o,              // [8][KS][4096][64]
    float* __restrict__ part_l,              // [8][KS][4096]
    int nchunk, int chunk_len)
{
    __shared__ __align__(16) unsigned short Pt[4][32 * 64];  // 16 KB total

    const int tid  = threadIdx.x;
    const int w    = tid >> 6;
    const int lane = tid & 63;
    const int quad = lane >> 4;
    const int l16  = lane & 15;
    const int l7   = l16 & 7;
    const int b     = blockIdx.z;
    const int chunk = blockIdx.y;
    const int i0   = blockIdx.x * 128;
    const int irow = i0 + w * 32;
    const int jb   = chunk * chunk_len;

    const unsigned short* kfb = kf + (size_t)b * 256 * 1024;
    const unsigned short* vfb = vf + (size_t)b * 64 * 4096;

    // Q fragments (B-operand of S^T) — coalesced reads from kf
    v8bf aq0[2], aq1[2];
    #pragma unroll
    for (int m = 0; m < 2; ++m) {
        const unsigned short* qr = kfb + (size_t)((irow >> 4) + m) * 1024 + lane * 8;
        aq0[m] = ld8(qr);
        aq1[m] = ld8(qr + 512);
    }

    // fixed stabilizer pre-scaled: negml2[m] = -||q_i||^2 * log2(e)
    float negml2[2];
    #pragma unroll
    for (int m = 0; m < 2; ++m) {
        float msq = 0.f;
        #pragma unroll
        for (int i = 0; i < 8; ++i) {
            float e0 = (float)aq0[m][i], e1 = (float)aq1[m][i];
            msq = fmaf(e0, e0, msq);
            msq = fmaf(e1, e1, msq);
        }
        msq += __shfl_xor(msq, 16);
        msq += __shfl_xor(msq, 32);
        negml2[m] = -msq * LOG2E;
    }

    v8bf ones;
    #pragma unroll
    for (int i = 0; i < 8; ++i) ones[i] = (__bf16)1.0f;

    v4f o[2][4];
    v4f lsum[2];
    #pragma unroll
    for (int m = 0; m < 2; ++m) {
        lsum[m][0]=0.f; lsum[m][1]=0.f; lsum[m][2]=0.f; lsum[m][3]=0.f;
        #pragma unroll
        for (int ct = 0; ct < 4; ++ct) { o[m][ct][0]=0.f; o[m][ct][1]=0.f; o[m][ct][2]=0.f; o[m][ct][3]=0.f; }
    }

    unsigned short* Pw = Pt[w];
    const int phalf = (quad & 1) * 4;
    const int pgq   = quad >> 1;

    for (int jj = 0; jj < chunk_len; jj += 64) {
        const int j0 = jb + jj;

        // ---- S^T = K Q^T (coalesced kf loads), exp2, store P^T ----
        #pragma unroll
        for (int jt = 0; jt < 4; ++jt) {
            const unsigned short* kr = kfb + (size_t)((j0 >> 4) + jt) * 1024 + lane * 8;
            v8bf bk0 = ld8(kr);
            v8bf bk1 = ld8(kr + 512);
            #pragma unroll
            for (int m = 0; m < 2; ++m) {
                v4f z; z[0]=0.f; z[1]=0.f; z[2]=0.f; z[3]=0.f;
                z = __builtin_amdgcn_mfma_f32_16x16x32_bf16(bk0, aq0[m], z, 0, 0, 0);
                z = __builtin_amdgcn_mfma_f32_16x16x32_bf16(bk1, aq1[m], z, 0, 0, 0);
                const float p0 = exp2f(fmaf(z[0], LOG2E, negml2[m]));
                const float p1 = exp2f(fmaf(z[1], LOG2E, negml2[m]));
                const float p2 = exp2f(fmaf(z[2], LOG2E, negml2[m]));
                const float p3 = exp2f(fmaf(z[3], LOG2E, negml2[m]));
                uint2 pk; pk.x = pkbf(p0, p1); pk.y = pkbf(p2, p3);
                const int pos = (2 * jt + pgq) ^ l7;
                *(uint2*)(Pw + (m * 16 + l16) * 64 + pos * 8 + phalf) = pk;
            }
        }

        // ---- P^T B-frags (wave-local; lgkmcnt ordering only) + MFMA sums ----
        v8bf pb0[2], pb1[2];
        #pragma unroll
        for (int m = 0; m < 2; ++m) {
            const unsigned short* pr = Pw + (m * 16 + l16) * 64;
            const int p0c = quad ^ l7;
            pb0[m] = ld8(pr + p0c * 8);
            pb1[m] = ld8(pr + (p0c ^ 4) * 8);
            lsum[m] = __builtin_amdgcn_mfma_f32_16x16x32_bf16(ones, pb0[m], lsum[m], 0, 0, 0);
            lsum[m] = __builtin_amdgcn_mfma_f32_16x16x32_bf16(ones, pb1[m], lsum[m], 0, 0, 0);
        }

        // ---- O^T += V^T P^T (coalesced vf loads) ----
        #pragma unroll
        for (int ct = 0; ct < 4; ++ct) {
            const unsigned short* vr = vfb + (size_t)((j0 >> 6) * 4 + ct) * 1024 + lane * 8;
            v8bf bv0 = ld8(vr);
            v8bf bv1 = ld8(vr + 512);
            #pragma unroll
            for (int m = 0; m < 2; ++m) {
                o[m][ct] = __builtin_amdgcn_mfma_f32_16x16x32_bf16(bv0, pb0[m], o[m][ct], 0, 0, 0);
                o[m][ct] = __builtin_amdgcn_mfma_f32_16x16x32_bf16(bv1, pb1[m], o[m][ct], 0, 0, 0);
            }
        }
    }

    // ---- epilogue ----
    const size_t pbase = (size_t)(b * nchunk + chunk) * NTOK + irow;
    #pragma unroll
    for (int m = 0; m < 2; ++m)
        if (quad == 0) part_l[pbase + m * 16 + l16] = lsum[m][0];
    float* po = part_o + pbase * 64;
    #pragma unroll
    for (int m = 0; m < 2; ++m)
        #pragma unroll
        for (int ct = 0; ct < 4; ++ct)
            *(v4f*)(po + (size_t)(m * 16 + l16) * 64 + ct * 16 + quad * 4) = o[m][ct];
}

// ---------------------------------------------------------------------------
// Combine: sum chunk partials, normalize, transpose, add x, store.
// Grid: (128 i-tiles of 32 rows, 8 batches) x 256 threads. KS compile-time.
// ---------------------------------------------------------------------------
template <int KS_>
__global__ __launch_bounds__(256) void combine_kernel(
    const float* __restrict__ part_o,  // [8][KS][4096][64]
    const float* __restrict__ part_l,  // [8][KS][4096]
    const float* __restrict__ x,       // [8][64][4096]
    float* __restrict__ out)           // [8][64][4096]
{
    __shared__ float Of[32 * 65];
    const int tid = threadIdx.x;
    const int b = blockIdx.y;
    const int i0 = blockIdx.x * 32;

    const int row = tid >> 3;          // 0..31
    const int col = (tid & 7) * 8;
    float acc[8];
    #pragma unroll
    for (int k = 0; k < 8; ++k) acc[k] = 0.f;
    float lt = 0.f;

    #pragma unroll
    for (int ch = 0; ch < KS_; ++ch) {
        const size_t base = (size_t)(b * KS_ + ch) * NTOK + i0 + row;
        lt += part_l[base];
        const float* po = part_o + base * 64 + col;
        float4 v0 = *(const float4*)(po);
        float4 v1 = *(const float4*)(po + 4);
        acc[0]+=v0.x; acc[1]+=v0.y; acc[2]+=v0.z; acc[3]+=v0.w;
        acc[4]+=v1.x; acc[5]+=v1.y; acc[6]+=v1.z; acc[7]+=v1.w;
    }
    const float inv = 1.f / lt;
    #pragma unroll
    for (int k = 0; k < 8; ++k) Of[row * 65 + col + k] = acc[k] * inv;
    __syncthreads();

    const int c    = tid >> 2;
    const int part = tid & 3;
    const float* xrow = x   + ((size_t)b * CCH + c) * NTOK + i0 + part * 8;
    float*       orow = out + ((size_t)b * CCH + c) * NTOK + i0 + part * 8;
    #pragma unroll
    for (int i4 = 0; i4 < 2; ++i4) {
        float4 xv = *(const float4*)(xrow + i4 * 4);
        float4 ov;
        ov.x = Of[(part * 8 + i4 * 4 + 0) * 65 + c] + xv.x;
        ov.y = Of[(part * 8 + i4 * 4 + 1) * 65 + c] + xv.y;
        ov.z = Of[(part * 8 + i4 * 4 + 2) * 65 + c] + xv.z;
        ov.w = Of[(part * 8 + i4 * 4 + 3) * 65 + c] + xv.w;
        *(float4*)(orow + i4 * 4) = ov;
    }
}

// ---------------------------------------------------------------------------
extern "C" void kernel_launch(void* const* d_in, const int* in_sizes, int n_in,
                              void* d_out, int out_size, void* d_ws, size_t ws_size,
                              hipStream_t stream) {
    const float* x = (const float*)d_in[0];
    const float* w = (const float*)d_in[1];
    float* out = (float*)d_out;

    const size_t frag_elems = (size_t)8 * 256 * 1024;       // 2M shorts = 4 MB
    unsigned short* kf = (unsigned short*)d_ws;
    unsigned short* vf = kf + frag_elems;
    char* rest = (char*)d_ws + 2 * frag_elems * sizeof(unsigned short);  // +8 MB

    int KS = 4;
    while (KS > 1) {
        size_t need = 2 * frag_elems * sizeof(unsigned short)
                    + (size_t)KS * ((size_t)8 * NTOK * CCH * 4 + (size_t)8 * NTOK * 4);
        if (need <= ws_size) break;
        KS >>= 1;
    }
    float* part_o = (float*)rest;
    float* part_l = (float*)(rest + (size_t)KS * 8 * NTOK * CCH * 4);

    dim3 gp(64, 8);
    prep_kernel<<<gp, 256, 0, stream>>>(x, w, kf, vf);
    dim3 gf(32, KS, 8);
    flash_kernel<<<gf, 256, 0, stream>>>(kf, vf, part_o, part_l, KS, NTOK / KS);
    dim3 gc(128, 8);
    if (KS == 4)      combine_kernel<4><<<gc, 256, 0, stream>>>(part_o, part_l, x, out);
    else if (KS == 2) combine_kernel<2><<<gc, 256, 0, stream>>>(part_o, part_l, x, out);
    else              combine_kernel<1><<<gc, 256, 0, stream>>>(part_o, part_l, x, out);
}